// Round 9
// baseline (164.027 us; speedup 1.0000x reference)
//
#include <hip/hip_runtime.h>

// Problem constants
#define HW_   36864      // 192*192
#define WI    192
#define HT    192
#define CIN   128
#define DK    256        // == D_V
#define NH    8
#define DKH   32         // channels per head
// TEMPER = 16 -> scale 1/16 = 0.0625
// Inputs/output are fp32 (established rounds 2-8).

using short4_ = __attribute__((ext_vector_type(4))) short;
using short8  = __attribute__((ext_vector_type(8))) short;
using float4_ = __attribute__((ext_vector_type(4))) float;

static __device__ __forceinline__ float b2f(unsigned short u) {
    union { unsigned int i; float f; } x; x.i = ((unsigned int)u) << 16; return x.f;
}
static __device__ __forceinline__ unsigned short f2b(float f) {
    union { float f; unsigned int i; } x; x.f = f;
    unsigned int r = x.i + 0x7FFFu + ((x.i >> 16) & 1u);   // round-nearest-even
    return (unsigned short)(r >> 16);
}

// ---------------------------------------------------------------------------
// Kernel 1: weights fp32 -> bf16 wqkv[8][96][128] (rows 0-31 q, 32-63 k,
// 64-95 v per head). 384 blocks, verified r4-r8.
// ---------------------------------------------------------------------------
__global__ __launch_bounds__(256) void convw_kernel(
    const float* __restrict__ wq,
    const float* __restrict__ wk,
    const float* __restrict__ wv,
    unsigned short* __restrict__ wqkv)
{
    int id = blockIdx.x * 256 + threadIdx.x;   // 98304 = 8*96*128
    int h   = id / 12288;
    int rem = id - h * 12288;
    int r   = rem >> 7;
    int c   = rem & 127;
    const float* __restrict__ s = (r < 32) ? wq : ((r < 64) ? wk : wv);
    wqkv[id] = f2b(s[(h * 32 + (r & 31)) * 128 + c]);
}

// ---------------------------------------------------------------------------
// Kernel 2: fused projection v3. Block = 256 thr (4 waves) = one 64-px tile,
// all 8 heads. B-side: x tile read once (fp32, coalesced), bf16-transposed
// through LDS (r8-verified), fragments pulled to registers -> LDS dead after
// ONE barrier. A-side: fragments straight from global bf16 wqkv per head
// (r5/r7-verified pattern, stride 128; 192 KB L2-resident, re-read by every
// wave -> L1/L2 hits). No per-head staging, no per-head barriers.
// LDS = 17.4 KB -> 8 blocks/CU; 32 waves/CU hides A-load latency.
// Epilogue r4-verified: S quad-reduce + pixel-major vbuf.
// ---------------------------------------------------------------------------
__global__ __launch_bounds__(256) void projfused3_kernel(
    const float* __restrict__ x,               // [128][HW] fp32
    const unsigned short* __restrict__ wqkv,   // [8][96][128] bf16
    unsigned short* __restrict__ vbuf,         // [8][HW][32] bf16
    float* __restrict__ sbuf)                  // [8][HW] fp32
{
    __shared__ unsigned short Bs[64 * 136];
    const int px0 = blockIdx.x * 64;
    const int t   = threadIdx.x;
    const int lane = t & 63, wave = t >> 6;
    const int col  = lane & 15, quad = lane >> 4;

    // ---- Stage B: Bs[p][c] = bf16(x[c][px0+p]); wave-uniform c, lane = p
    //      -> coalesced 256B global reads per wave. ----
    #pragma unroll 4
    for (int i = 0; i < 32; ++i) {
        int id = i * 256 + t;
        int c = id >> 6, p = id & 63;
        Bs[p * 136 + c] = f2b(x[c * HW_ + px0 + p]);
    }
    __syncthreads();                           // the ONLY barrier

    // ---- B fragments: B[k][n], lane holds n = wave*16+col, k = quad*8+j ----
    short8 bfrag[4];
    {
        int n = wave * 16 + col;
        #pragma unroll
        for (int kt = 0; kt < 4; ++kt)
            bfrag[kt] = *(const short8*)&Bs[n * 136 + kt * 32 + quad * 8];
    }

    const int px = px0 + wave * 16 + col;
    for (int head = 0; head < 8; ++head) {
        const unsigned short* __restrict__ Ag = wqkv + head * 96 * 128;

        float4_ acc[6];
        #pragma unroll
        for (int mt = 0; mt < 6; ++mt)
            acc[mt] = (float4_){0.f, 0.f, 0.f, 0.f};

        #pragma unroll
        for (int mt = 0; mt < 6; ++mt) {
            #pragma unroll
            for (int kt = 0; kt < 4; ++kt) {
                short8 a = *(const short8*)&Ag[(mt * 16 + col) * 128 + kt * 32 + quad * 8];
                acc[mt] = __builtin_amdgcn_mfma_f32_16x16x32_bf16(a, bfrag[kt], acc[mt], 0, 0, 0);
            }
        }

        // ---- Epilogue (r4-verified). C/D: col = pixel, row = quad*4+reg ----
        float s = 0.f;
        #pragma unroll
        for (int reg = 0; reg < 4; ++reg)
            s += acc[0][reg] * acc[2][reg]
               + acc[1][reg] * acc[3][reg];
        s += __shfl_xor(s, 16, 64);
        s += __shfl_xor(s, 32, 64);
        if (quad == 0) sbuf[head * HW_ + px] = s;
        unsigned short* vp = vbuf + ((size_t)head * HW_ + px) * 32;
        short4_ v0, v1;
        #pragma unroll
        for (int reg = 0; reg < 4; ++reg) {
            v0[reg] = (short)f2b(acc[4][reg]);
            v1[reg] = (short)f2b(acc[5][reg]);
        }
        *(short4_*)&vp[quad * 4]      = v0;
        *(short4_*)&vp[16 + quad * 4] = v1;
    }
}

// ---------------------------------------------------------------------------
// Kernel 3: regional softmax + weighted 3x3 gather (verified r4-r8).
// Block = 64 px x 4 ch-groups; one coalesced 16B short8 load per neighbor;
// d-major fp32 output via LDS transpose (stride 65).
// ---------------------------------------------------------------------------
__global__ __launch_bounds__(256) void attn_kernel(
    const unsigned short* __restrict__ vbuf,  // [8][HW][32] bf16
    const float* __restrict__ sbuf,           // [8][HW]
    float* __restrict__ out)                  // [256][HW] fp32
{
    __shared__ float tr[32][65];
    const int b    = blockIdx.x;              // 4608 = 576 px-tiles * 8 heads
    const int tile = b % 576;
    const int head = b / 576;
    const int t    = threadIdx.x;
    const int pxl  = t >> 2;                  // 0..63
    const int cg   = t & 3;                   // channel group (8 ch)
    const int px   = tile * 64 + pxl;
    const int y    = px / WI;
    const int xx   = px - y * WI;

    const float* __restrict__ Sh = sbuf + head * HW_;

    float w[9];
    int   np[9];
    float m = -1e30f;
    #pragma unroll
    for (int r = 0; r < 9; ++r) {
        int dy = r / 3 - 1, dx = r % 3 - 1;
        int ny = y + dy, nx = xx + dx;
        bool inb = (ny >= 0) && (ny < HT) && (nx >= 0) && (nx < WI);
        int idx = inb ? (ny * WI + nx) : px;  // safe index; weight zeroed below
        np[r] = idx;
        float val = inb ? (Sh[idx] * 0.0625f) : 0.0f;
        w[r] = val;
        m = fmaxf(m, val);
    }
    float wsum = 0.f;
    #pragma unroll
    for (int r = 0; r < 9; ++r) {
        float e = __expf(w[r] - m);
        w[r] = e;
        wsum += e;
    }
    float inv = 1.0f / wsum;
    #pragma unroll
    for (int r = 0; r < 9; ++r) {
        int dy = r / 3 - 1, dx = r % 3 - 1;
        int ny = y + dy, nx = xx + dx;
        bool inb = (ny >= 0) && (ny < HT) && (nx >= 0) && (nx < WI);
        w[r] = inb ? (w[r] * inv) : 0.0f;
    }

    const unsigned short* __restrict__ vb = vbuf + (size_t)head * HW_ * 32;
    float acc[8] = {0.f, 0.f, 0.f, 0.f, 0.f, 0.f, 0.f, 0.f};
    #pragma unroll
    for (int r = 0; r < 9; ++r) {
        short8 v8 = *(const short8*)&vb[np[r] * 32 + cg * 8];
        #pragma unroll
        for (int j = 0; j < 8; ++j)
            acc[j] = fmaf(w[r], b2f((unsigned short)v8[j]), acc[j]);
    }
    #pragma unroll
    for (int j = 0; j < 8; ++j)
        tr[cg * 8 + j][pxl] = acc[j];
    __syncthreads();

    // write-out: thread t -> channel ch = t>>3, px chunk c8 = t&7 (8 px)
    const int ch = t >> 3, c8 = t & 7;
    const int px0 = tile * 64;
    const size_t obase = (size_t)(head * DKH + ch) * HW_ + px0 + c8 * 8;
    float4_ o0, o1;
    #pragma unroll
    for (int j = 0; j < 4; ++j) {
        o0[j] = tr[ch][c8 * 8 + j];
        o1[j] = tr[ch][c8 * 8 + 4 + j];
    }
    float* o = out + obase;
    *(float4_*)&o[0] = o0;
    *(float4_*)&o[4] = o1;
}

// ---------------------------------------------------------------------------
// Workspace layout:
//   [0, 196608)              wqkv : 8*96*128 bf16
//   [196608, 19071104)       vbuf : 8*36864*32 bf16 (pixel-major)
//   [19071104, 20250752)     sbuf : 8*36864 fp32
// ---------------------------------------------------------------------------
extern "C" void kernel_launch(void* const* d_in, const int* in_sizes, int n_in,
                              void* d_out, int out_size, void* d_ws, size_t ws_size,
                              hipStream_t stream) {
    const float* x  = (const float*)d_in[0];
    const float* wq = (const float*)d_in[1];
    const float* wk = (const float*)d_in[2];
    const float* wv = (const float*)d_in[3];

    char* ws = (char*)d_ws;
    unsigned short* wqkv = (unsigned short*)ws;
    unsigned short* vbuf = (unsigned short*)(ws + 196608);
    float*          sbuf = (float*)(ws + 19071104);

    convw_kernel<<<384, 256, 0, stream>>>(wq, wk, wv, wqkv);
    projfused3_kernel<<<576, 256, 0, stream>>>(x, wqkv, vbuf, sbuf);
    attn_kernel<<<4608, 256, 0, stream>>>(vbuf, sbuf, (float*)d_out);
}